// Round 16
// baseline (167.545 us; speedup 1.0000x reference)
//
#include <hip/hip_runtime.h>
#include <hip/hip_bf16.h>

#define NPTS 262144
#define DDIM 64
#define KCB  1024
#define CHUNK 128            // codebook rows per staged chunk (16 KB fp16 image)
#define NCHUNK (KCB / CHUNK) // 8
#define GPC (CHUNK / 16)     // 8 groups (16 cols) per chunk
#define PPB 256              // points per block (512 threads, 8 waves x 32 pts)

typedef __attribute__((ext_vector_type(8))) _Float16 half8;
typedef __attribute__((ext_vector_type(4))) float f32x4;

static __device__ __forceinline__ bool beats(float sa, int ka, float sb, int kb) {
    return (sa > sb) || (sa == sb && ka < kb);
}
static __device__ __forceinline__ float keyf(float acc, unsigned inv) {
    return __uint_as_float((__float_as_uint(acc) & 0xFFFFFFC0u) | inv);  // v_and_or_b32
}

// prep 1: c2h[k] = 256 - 0.5*||fp16(c_k)||^2  (acc-init for the surrogate distance)
//         c2x[k] = 256 - 0.5*||c_k||^2        (exact, for the final re-rank)
__global__ __launch_bounds__(256) void c2n_kernel(const float* __restrict__ cb,
                                                  float* __restrict__ c2h,
                                                  float* __restrict__ c2x) {
    int k = blockIdx.x * blockDim.x + threadIdx.x;
    if (k >= KCB) return;
    const float4* row = (const float4*)(cb + (size_t)k * DDIM);
    float sh = 0.f, sx = 0.f;
#pragma unroll
    for (int j = 0; j < DDIM / 4; ++j) {
        float4 a = row[j];
        float v[4] = {a.x, a.y, a.z, a.w};
#pragma unroll
        for (int e = 0; e < 4; ++e) {
            float h = (float)(_Float16)v[e];
            sh = __builtin_fmaf(h, h, sh);
            sx = __builtin_fmaf(v[e], v[e], sx);
        }
    }
    c2h[k] = 256.0f - 0.5f * sh;
    c2x[k] = 256.0f - 0.5f * sx;
}

// prep 2: pack codebook into fp16 fragment-layout image, 16KB chunks.
// Chunk c (128 rows): ushort[8192]; idx = g*1024 + ks*512 + q*128 + col*8 + j
//   (row = c*128 + g*16 + col, dim d = ks*32 + q*8 + j)
// => B read for lane l, group g: byte = g*2048 + l*16 (+1024 for ks=1)
__global__ __launch_bounds__(256) void pack_kernel(const float* __restrict__ cb,
                                                   unsigned short* __restrict__ G) {
    int t = blockIdx.x * 256 + threadIdx.x;  // 8192 threads: (row, d8)
    int r = t >> 3, d8 = t & 7;
    const float4* src = (const float4*)(cb + (size_t)r * DDIM + d8 * 8);
    float4 v0 = src[0], v1 = src[1];
    float vv[8] = {v0.x, v0.y, v0.z, v0.w, v1.x, v1.y, v1.z, v1.w};
    half8 h;
#pragma unroll
    for (int j = 0; j < 8; ++j) h[j] = (_Float16)vv[j];
    int c = r >> 7, g = (r >> 4) & 7, col = r & 15;
    int ks = d8 >> 2, q = d8 & 3;
    size_t base = (size_t)c * 8192 + g * 1024 + ks * 512 + q * 128 + col * 8;
    *(half8*)(G + base) = h;
}

__global__ __launch_bounds__(512, 4) void vq_main(const float* __restrict__ x,
                                                  const float* __restrict__ cb,
                                                  const float* __restrict__ c2h,
                                                  const float* __restrict__ c2x,
                                                  const unsigned short* __restrict__ G,
                                                  float* __restrict__ out) {
    __shared__ unsigned short frag[2][CHUNK * DDIM];  // 2 x 16KB double buffer
    __shared__ float lds_c2f[KCB];                    // 4KB acc-init values
    __shared__ int lds_bk1[PPB];
    __shared__ int lds_bk2[PPB];
    __shared__ int lds_bk3[PPB];

    const int tid = threadIdx.x;
    const int lane = tid & 63;
    const int wave = tid >> 6;       // 0..7, each owns 32 points
    const int b15 = lane & 15;
    const int q = lane >> 4;
    const int blk_base = blockIdx.x * PPB;
    const int wave_base = blk_base + wave * 32;
    const int lane_off = lane * 16;  // byte offset of this lane's B-fragment slot

    // ---- A fragments: fp16 hi/lo of this wave's points (2 tiles x 2 ksteps) ----
    half8 Ah[2][2], Al[2][2];
#pragma unroll
    for (int t = 0; t < 2; ++t) {
        const float* xr = x + (size_t)(wave_base + t * 16 + b15) * DDIM + q * 8;
#pragma unroll
        for (int ks = 0; ks < 2; ++ks) {
            float4 v0 = *(const float4*)(xr + ks * 32);
            float4 v1 = *(const float4*)(xr + ks * 32 + 4);
            float vv[8] = {v0.x, v0.y, v0.z, v0.w, v1.x, v1.y, v1.z, v1.w};
            half8 h, l;
#pragma unroll
            for (int j = 0; j < 8; ++j) {
                _Float16 hh = (_Float16)vv[j];
                h[j] = hh;
                l[j] = (_Float16)(vv[j] - (float)hh);
            }
            Ah[t][ks] = h;
            Al[t][ks] = l;
        }
    }

    // top-3 keys per point (8 points/lane), positive-float keys, low6 = 63-group
    float b1[8], b2[8], b3[8];
#pragma unroll
    for (int i = 0; i < 8; ++i) { b1[i] = 0.0f; b2[i] = 0.0f; b3[i] = 0.0f; }

    // stage 16KB chunk: 512 threads x 2 x 16B global_load_lds
#define STAGE(cc, buf)                                                                     \
    {                                                                                      \
        const unsigned char* gsrc = (const unsigned char*)G + (size_t)(cc) * 16384 + tid * 16; \
        unsigned char* ldst = (unsigned char*)&frag[buf][0] + tid * 16;                    \
        _Pragma("unroll") for (int it = 0; it < 2; ++it)                                   \
            __builtin_amdgcn_global_load_lds(                                              \
                (const __attribute__((address_space(1))) unsigned int*)(gsrc + it * 8192), \
                (__attribute__((address_space(3))) unsigned int*)(ldst + it * 8192),       \
                16, 0, 0);                                                                 \
    }

    // ---- prologue: stage chunk 0; fill c2h LDS table ----
    STAGE(0, 0);
    lds_c2f[tid] = c2h[tid];
    lds_c2f[tid + 512] = c2h[tid + 512];
    __syncthreads();

    for (int cc = 0; cc < NCHUNK; ++cc) {
        const int cur = cc & 1;
        if (cc + 1 < NCHUNK) STAGE(cc + 1, cur ^ 1);
        const unsigned char* fb = (const unsigned char*)&frag[cur][0];

#pragma unroll
        for (int g = 0; g < GPC; ++g) {
            const int gg = cc * GPC + g;
            const unsigned inv = 63u - (unsigned)gg;
            const unsigned char* p_ = fb + (size_t)g * 2048 + lane_off;
            const half8 B0 = *(const half8*)(p_);
            const half8 B1 = *(const half8*)(p_ + 1024);
            const float cg = lds_c2f[gg * 16 + b15];
            const f32x4 cvec = (f32x4){cg, cg, cg, cg};

            // exact surrogate dot: (ah+al)*ch over K=64 -> 8 MFMAs, two 4-chains
            f32x4 acc[2];
            __builtin_amdgcn_s_setprio(1);
#pragma unroll
            for (int t = 0; t < 2; ++t) {
                acc[t] = __builtin_amdgcn_mfma_f32_16x16x32_f16(Ah[t][0], B0, cvec, 0, 0, 0);
                acc[t] = __builtin_amdgcn_mfma_f32_16x16x32_f16(Al[t][0], B0, acc[t], 0, 0, 0);
                acc[t] = __builtin_amdgcn_mfma_f32_16x16x32_f16(Ah[t][1], B1, acc[t], 0, 0, 0);
                acc[t] = __builtin_amdgcn_mfma_f32_16x16x32_f16(Al[t][1], B1, acc[t], 0, 0, 0);
            }
            __builtin_amdgcn_s_setprio(0);

            // top-3 insert: new3=med3(kk,b2,b3); new2=med3(kk,b1,b2); new1=max(b1,kk)
#pragma unroll
            for (int t = 0; t < 2; ++t)
#pragma unroll
                for (int r = 0; r < 4; ++r) {
                    const int i = t * 4 + r;
                    const float kk = keyf(acc[t][r], inv);
                    const float n3 = __builtin_amdgcn_fmed3f(kk, b2[i], b3[i]);
                    const float n2 = __builtin_amdgcn_fmed3f(kk, b1[i], b2[i]);
                    b1[i] = fmaxf(b1[i], kk);
                    b2[i] = n2;
                    b3[i] = n3;
                }
        }
        __syncthreads();  // next chunk's loads landed under compute; flip buffers
    }
#undef STAGE

    // ---- decode candidate k, then merge top-3 across the 16 col-lanes ----
    unsigned int K1[8], K2[8], K3[8];
    int I1[8], I2[8], I3[8];
#pragma unroll
    for (int i = 0; i < 8; ++i) {
        K1[i] = __float_as_uint(b1[i]); I1[i] = (int)(63u - (K1[i] & 63u)) * 16 + b15;
        K2[i] = __float_as_uint(b2[i]); I2[i] = (int)(63u - (K2[i] & 63u)) * 16 + b15;
        K3[i] = __float_as_uint(b3[i]); I3[i] = (int)(63u - (K3[i] & 63u)) * 16 + b15;
    }
    // butterfly: insert the partner's sorted triple, element by element
#pragma unroll
    for (int m = 1; m < 16; m <<= 1) {
#pragma unroll
        for (int i = 0; i < 8; ++i) {
            unsigned int ok[3]; int oi[3];
            ok[0] = __shfl_xor(K1[i], m); oi[0] = __shfl_xor(I1[i], m);
            ok[1] = __shfl_xor(K2[i], m); oi[1] = __shfl_xor(I2[i], m);
            ok[2] = __shfl_xor(K3[i], m); oi[2] = __shfl_xor(I3[i], m);
#pragma unroll
            for (int s = 0; s < 3; ++s) {
                const unsigned int kk = ok[s]; const int ii = oi[s];
                bool c1 = (kk > K1[i]) || (kk == K1[i] && ii < I1[i]);
                bool c2 = (kk > K2[i]) || (kk == K2[i] && ii < I2[i]);
                bool c3 = (kk > K3[i]) || (kk == K3[i] && ii < I3[i]);
                unsigned int nk3 = c2 ? K2[i] : (c3 ? kk : K3[i]);
                int ni3 = c2 ? I2[i] : (c3 ? ii : I3[i]);
                unsigned int nk2 = c1 ? K1[i] : (c2 ? kk : K2[i]);
                int ni2 = c1 ? I1[i] : (c2 ? ii : I2[i]);
                unsigned int nk1 = c1 ? kk : K1[i];
                int ni1 = c1 ? ii : I1[i];
                K1[i] = nk1; I1[i] = ni1; K2[i] = nk2; I2[i] = ni2; K3[i] = nk3; I3[i] = ni3;
            }
        }
    }

    if (b15 == 0) {
#pragma unroll
        for (int t = 0; t < 2; ++t)
#pragma unroll
            for (int r = 0; r < 4; ++r) {
                int pl = wave * 32 + t * 16 + q * 4 + r;
                lds_bk1[pl] = I1[t * 4 + r];
                lds_bk2[pl] = I2[t * 4 + r];
                lds_bk3[pl] = I3[t * 4 + r];
            }
    }
    __syncthreads();

    // ---- exact f32 re-rank vs TRUE codebook: 2 threads/point (t0: k1, t1: k2+k3) ----
    const int pid = tid >> 1;
    const int p = blk_base + pid;
    const bool first = ((tid & 1) == 0);
    const int ka = first ? lds_bk1[pid] : lds_bk2[pid];
    const int kb = lds_bk3[pid];  // only used by odd thread
    const float4* xr = (const float4*)(x + (size_t)p * DDIM);
    const float4* ca = (const float4*)(cb + (size_t)ka * DDIM);
    const float4* cbp = (const float4*)(cb + (size_t)kb * DDIM);
    float daa = 0.f, dab = 0.f, dba = 0.f, dbb = 0.f;
#pragma unroll
    for (int j = 0; j < 16; ++j) {
        float4 xv = xr[j];
        float4 u = ca[j];
        daa = __builtin_fmaf(xv.x, u.x, daa); dab = __builtin_fmaf(xv.y, u.y, dab);
        daa = __builtin_fmaf(xv.z, u.z, daa); dab = __builtin_fmaf(xv.w, u.w, dab);
        if (!first) {
            float4 w = cbp[j];
            dba = __builtin_fmaf(xv.x, w.x, dba); dbb = __builtin_fmaf(xv.y, w.y, dbb);
            dba = __builtin_fmaf(xv.z, w.z, dba); dbb = __builtin_fmaf(xv.w, w.w, dbb);
        }
    }
    float aa = (daa + dab) + c2x[ka];
    int kaa = ka;
    if (!first) {  // odd thread: fold k3 into its candidate
        float ab = (dba + dbb) + c2x[kb];
        if (beats(ab, kb, aa, kaa)) { aa = ab; kaa = kb; }
    }
    float oa = __shfl_xor(aa, 1);
    int okk = __shfl_xor(kaa, 1);
    float a1 = first ? aa : oa; int k1 = first ? kaa : okk;
    float a2 = first ? oa : aa; int k2 = first ? okk : kaa;
    int kf = beats(a1, k1, a2, k2) ? k1 : k2;

    if (first) out[p] = (float)kf;
    const float4* cf = (const float4*)(cb + (size_t)kf * DDIM + (tid & 1) * 32);
    float4* qo = (float4*)(out + NPTS + (size_t)p * DDIM + (tid & 1) * 32);
#pragma unroll
    for (int j = 0; j < 8; ++j) qo[j] = cf[j];
}

extern "C" void kernel_launch(void* const* d_in, const int* in_sizes, int n_in,
                              void* d_out, int out_size, void* d_ws, size_t ws_size,
                              hipStream_t stream) {
    const float* x = (const float*)d_in[0];
    const float* cb = (const float*)d_in[1];
    float* c2h = (float*)d_ws;                                      // 4 KB
    float* c2x = (float*)((char*)d_ws + 4096);                      // 4 KB
    unsigned short* G = (unsigned short*)((char*)d_ws + 8192);      // 128 KB image

    hipLaunchKernelGGL(c2n_kernel, dim3(KCB / 256), dim3(256), 0, stream, cb, c2h, c2x);
    hipLaunchKernelGGL(pack_kernel, dim3(KCB * 8 / 256), dim3(256), 0, stream, cb, G);
    hipLaunchKernelGGL(vq_main, dim3(NPTS / PPB), dim3(512), 0, stream,
                       x, cb, c2h, c2x, G, (float*)d_out);
}

// Round 17
// 135.208 us; speedup vs baseline: 1.2392x; 1.2392x over previous
//
#include <hip/hip_runtime.h>
#include <hip/hip_bf16.h>

#define NPTS 262144
#define DDIM 64
#define KCB  1024
#define CHUNK 128            // codebook rows per staged chunk (32 KB image)
#define NCHUNK (KCB / CHUNK) // 8
#define GPC (CHUNK / 16)     // 8 groups (16 cols) per chunk
#define PPB 256              // points per block (512 threads, 8 waves x 32 pts)

typedef __attribute__((ext_vector_type(8))) short short8;
typedef __attribute__((ext_vector_type(4))) float f32x4;

static __device__ __forceinline__ unsigned short f2bf_rne(float f) {
    union { float f; unsigned u; } v; v.f = f;
    unsigned r = v.u + 0x7FFFu + ((v.u >> 16) & 1u);
    return (unsigned short)(r >> 16);
}
static __device__ __forceinline__ float bf2f(unsigned short h) {
    union { unsigned u; float f; } v; v.u = ((unsigned)h) << 16;
    return v.f;
}
static __device__ __forceinline__ bool beats(float sa, int ka, float sb, int kb) {
    return (sa > sb) || (sa == sb && ka < kb);
}
static __device__ __forceinline__ float keyf(float acc, unsigned inv) {
    return __uint_as_float((__float_as_uint(acc) & 0xFFFFFFC0u) | inv);  // v_and_or_b32
}

// merged prep: pack codebook into bf16 hi/lo fragment image (r9 layout) AND
// compute c2n[k] = 256 - 0.5*||c_k||^2 via 8-lane shuffle reduce.
// Chunk c (128 rows): ushort[16384] = [hi 8192][lo 8192];
// idx = g*1024 + ks*512 + q*128 + col*8 + j  (row = c*128+g*16+col, d = ks*32+q*8+j)
__global__ __launch_bounds__(256) void prep_kernel(const float* __restrict__ cb,
                                                   unsigned short* __restrict__ G,
                                                   float* __restrict__ c2n) {
    int t = blockIdx.x * 256 + threadIdx.x;  // 8192 threads: (row, d8)
    int r = t >> 3, d8 = t & 7;
    const float4* src = (const float4*)(cb + (size_t)r * DDIM + d8 * 8);
    float4 v0 = src[0], v1 = src[1];
    float vv[8] = {v0.x, v0.y, v0.z, v0.w, v1.x, v1.y, v1.z, v1.w};
    short8 h, l;
    float s = 0.f;
#pragma unroll
    for (int j = 0; j < 8; ++j) {
        unsigned short hb = f2bf_rne(vv[j]);
        h[j] = (short)hb;
        l[j] = (short)f2bf_rne(vv[j] - bf2f(hb));
        s = __builtin_fmaf(vv[j], vv[j], s);
    }
    int c = r >> 7, g = (r >> 4) & 7, col = r & 15;
    int ks = d8 >> 2, q = d8 & 3;
    size_t base = (size_t)c * 16384 + g * 1024 + ks * 512 + q * 128 + col * 8;
    *(short8*)(G + base) = h;
    *(short8*)(G + base + 8192) = l;
    // row-sum across the 8 lanes holding this row (consecutive lanes)
    s += __shfl_xor(s, 1);
    s += __shfl_xor(s, 2);
    s += __shfl_xor(s, 4);
    if (d8 == 0) c2n[r] = 256.0f - 0.5f * s;
}

struct BFrag { short8 h0, l0, h1, l1; };

__global__ __launch_bounds__(512, 4) void vq_main(const float* __restrict__ x,
                                                  const float* __restrict__ cb,
                                                  const float* __restrict__ c2n,
                                                  const unsigned short* __restrict__ G,
                                                  float* __restrict__ out) {
    __shared__ unsigned short frag[2][CHUNK * DDIM * 2];  // 2 x 32KB double buffer
    __shared__ float lds_c2f[KCB];                        // 4KB acc-init values
    __shared__ int lds_bk1[PPB];
    __shared__ int lds_bk2[PPB];

    const int tid = threadIdx.x;
    const int lane = tid & 63;
    const int wave = tid >> 6;       // 0..7, each owns 32 points
    const int b15 = lane & 15;
    const int q = lane >> 4;
    const int blk_base = blockIdx.x * PPB;
    const int wave_base = blk_base + wave * 32;
    const int lane_off = lane * 16;  // byte offset of this lane's B-fragment slot

    // ---- A fragments: 2 point-tiles x 2 ksteps x (hi,lo) = 32 VGPR, resident ----
    short8 Ahi[2][2], Alo[2][2];
#pragma unroll
    for (int t = 0; t < 2; ++t) {
        const float* xr = x + (size_t)(wave_base + t * 16 + b15) * DDIM + q * 8;
#pragma unroll
        for (int ks = 0; ks < 2; ++ks) {
            float4 v0 = *(const float4*)(xr + ks * 32);
            float4 v1 = *(const float4*)(xr + ks * 32 + 4);
            float vv[8] = {v0.x, v0.y, v0.z, v0.w, v1.x, v1.y, v1.z, v1.w};
            short8 h, l;
#pragma unroll
            for (int j = 0; j < 8; ++j) {
                unsigned short hb = f2bf_rne(vv[j]);
                h[j] = (short)hb;
                l[j] = (short)f2bf_rne(vv[j] - bf2f(hb));
            }
            Ahi[t][ks] = h;
            Alo[t][ks] = l;
        }
    }

    // top-2 keys per point (8 points/lane), positive-float keys, low6 = 63-group
    float b1[8], b2[8];
#pragma unroll
    for (int i = 0; i < 8; ++i) { b1[i] = 0.0f; b2[i] = 0.0f; }

    // stage 32KB chunk: 512 threads x 4 x 16B global_load_lds
#define STAGE(cc, buf)                                                                     \
    {                                                                                      \
        const unsigned char* gsrc = (const unsigned char*)G + (size_t)(cc) * 32768 + tid * 16; \
        unsigned char* ldst = (unsigned char*)&frag[buf][0] + tid * 16;                    \
        _Pragma("unroll") for (int it = 0; it < 4; ++it)                                   \
            __builtin_amdgcn_global_load_lds(                                              \
                (const __attribute__((address_space(1))) unsigned int*)(gsrc + it * 8192), \
                (__attribute__((address_space(3))) unsigned int*)(ldst + it * 8192),       \
                16, 0, 0);                                                                 \
    }
#define LOADB(dst, fb, g)                                               \
    {                                                                   \
        const unsigned char* p_ = (fb) + (size_t)(g) * 2048 + lane_off; \
        (dst).h0 = *(const short8*)(p_);                                \
        (dst).l0 = *(const short8*)(p_ + 16384);                        \
        (dst).h1 = *(const short8*)(p_ + 1024);                         \
        (dst).l1 = *(const short8*)(p_ + 17408);                        \
    }
    // 12 MFMA (bf16x3, K=64, 2 tiles); shared cvec as C of each tile's first MFMA
#define COMPUTE(acc, B, cvec)                                                                    \
    {                                                                                            \
        _Pragma("unroll") for (int t = 0; t < 2; ++t) {                                          \
            acc[t] = __builtin_amdgcn_mfma_f32_16x16x32_bf16(Ahi[t][0], (B).h0, cvec, 0, 0, 0);  \
            acc[t] = __builtin_amdgcn_mfma_f32_16x16x32_bf16(Ahi[t][0], (B).l0, acc[t], 0, 0, 0);\
            acc[t] = __builtin_amdgcn_mfma_f32_16x16x32_bf16(Alo[t][0], (B).h0, acc[t], 0, 0, 0);\
            acc[t] = __builtin_amdgcn_mfma_f32_16x16x32_bf16(Ahi[t][1], (B).h1, acc[t], 0, 0, 0);\
            acc[t] = __builtin_amdgcn_mfma_f32_16x16x32_bf16(Ahi[t][1], (B).l1, acc[t], 0, 0, 0);\
            acc[t] = __builtin_amdgcn_mfma_f32_16x16x32_bf16(Alo[t][1], (B).h1, acc[t], 0, 0, 0);\
        }                                                                                        \
    }

    // ---- prologue: stage chunk 0; fill c2n LDS table ----
    STAGE(0, 0);
    lds_c2f[tid] = c2n[tid];
    lds_c2f[tid + 512] = c2n[tid + 512];
    __syncthreads();

    for (int cc = 0; cc < NCHUNK; ++cc) {
        const int cur = cc & 1;
        if (cc + 1 < NCHUNK) STAGE(cc + 1, cur ^ 1);
        const unsigned char* fb = (const unsigned char*)&frag[cur][0];

        // batched acc-init reads: one lgkm point for the whole chunk
        float cg[GPC];
#pragma unroll
        for (int g = 0; g < GPC; ++g) cg[g] = lds_c2f[(cc * GPC + g) * 16 + b15];

        // 4 pairs of groups per chunk
#pragma unroll
        for (int j = 0; j < 4; ++j) {
            const int g0 = 2 * j, g1 = 2 * j + 1;
            const unsigned inv0 = 63u - (unsigned)(cc * GPC + g0);
            BFrag Ba, Bb;
            LOADB(Ba, fb, g0);
            LOADB(Bb, fb, g1);

            f32x4 acc0[2];
            const f32x4 cvec0 = (f32x4){cg[g0], cg[g0], cg[g0], cg[g0]};
            COMPUTE(acc0, Ba, cvec0);
            f32x4 acc1[2];
            const f32x4 cvec1 = (f32x4){cg[g1], cg[g1], cg[g1], cg[g1]};
            COMPUTE(acc1, Bb, cvec1);

            // paired top-2 update: {b1,ka,kb} -> max3 / med3; b2 = max(b2, med)
#pragma unroll
            for (int t = 0; t < 2; ++t)
#pragma unroll
                for (int r = 0; r < 4; ++r) {
                    const int i = t * 4 + r;
                    const float ka = keyf(acc0[t][r], inv0);
                    const float kb = keyf(acc1[t][r], inv0 - 1u);
                    const float med = __builtin_amdgcn_fmed3f(b1[i], ka, kb);
                    float nb1;
                    asm("v_max3_f32 %0, %1, %2, %3"
                        : "=v"(nb1) : "v"(b1[i]), "v"(ka), "v"(kb));
                    b1[i] = nb1;
                    b2[i] = fmaxf(b2[i], med);
                }
        }
        __syncthreads();  // loads for chunk cc+1 landed under compute; flip buffers
    }
#undef STAGE
#undef LOADB
#undef COMPUTE

    // ---- decode candidate k, then merge top-2 across the 16 col-lanes ----
    unsigned int K1[8], K2[8];
    int I1[8], I2[8];
#pragma unroll
    for (int i = 0; i < 8; ++i) {
        K1[i] = __float_as_uint(b1[i]); I1[i] = (int)(63u - (K1[i] & 63u)) * 16 + b15;
        K2[i] = __float_as_uint(b2[i]); I2[i] = (int)(63u - (K2[i] & 63u)) * 16 + b15;
    }
#pragma unroll
    for (int m = 1; m < 16; m <<= 1) {
#pragma unroll
        for (int i = 0; i < 8; ++i) {
            unsigned int o1 = __shfl_xor(K1[i], m); int oi1 = __shfl_xor(I1[i], m);
            unsigned int o2 = __shfl_xor(K2[i], m); int oi2 = __shfl_xor(I2[i], m);
            bool ob = (o1 > K1[i]) || (o1 == K1[i] && oi1 < I1[i]);
            unsigned int nk1, nk2; int ni1, ni2;
            if (ob) {
                nk1 = o1; ni1 = oi1;
                bool sb = (K1[i] > o2) || (K1[i] == o2 && I1[i] < oi2);
                nk2 = sb ? K1[i] : o2; ni2 = sb ? I1[i] : oi2;
            } else {
                nk1 = K1[i]; ni1 = I1[i];
                bool sb = (o1 > K2[i]) || (o1 == K2[i] && oi1 < I2[i]);
                nk2 = sb ? o1 : K2[i]; ni2 = sb ? oi1 : I2[i];
            }
            K1[i] = nk1; I1[i] = ni1; K2[i] = nk2; I2[i] = ni2;
        }
    }

    if (b15 == 0) {
#pragma unroll
        for (int t = 0; t < 2; ++t)
#pragma unroll
            for (int r = 0; r < 4; ++r) {
                int pl = wave * 32 + t * 16 + q * 4 + r;
                lds_bk1[pl] = I1[t * 4 + r];
                lds_bk2[pl] = I2[t * 4 + r];
            }
    }
    __syncthreads();

    // ---- exact f32 re-rank: 2 threads per point, one candidate each ----
    const int pid = tid >> 1;
    const int p = blk_base + pid;
    const int ksel = (tid & 1) ? lds_bk2[pid] : lds_bk1[pid];
    const float4* xr = (const float4*)(x + (size_t)p * DDIM);
    const float4* cr = (const float4*)(cb + (size_t)ksel * DDIM);
    float da = 0.f, db = 0.f;
#pragma unroll
    for (int j = 0; j < 16; ++j) {
        float4 xv = xr[j];
        float4 u = cr[j];
        da = __builtin_fmaf(xv.x, u.x, da); db = __builtin_fmaf(xv.y, u.y, db);
        da = __builtin_fmaf(xv.z, u.z, da); db = __builtin_fmaf(xv.w, u.w, db);
    }
    float a = (da + db) + lds_c2f[ksel];
    float oa = __shfl_xor(a, 1);
    int ok = __shfl_xor(ksel, 1);
    const bool first = ((tid & 1) == 0);
    float a1 = first ? a : oa; int k1 = first ? ksel : ok;
    float a2 = first ? oa : a; int k2 = first ? ok : ksel;
    int kf = beats(a1, k1, a2, k2) ? k1 : k2;

    if (first) out[p] = (float)kf;
    const float4* cf = (const float4*)(cb + (size_t)kf * DDIM + (tid & 1) * 32);
    float4* qo = (float4*)(out + NPTS + (size_t)p * DDIM + (tid & 1) * 32);
#pragma unroll
    for (int j = 0; j < 8; ++j) qo[j] = cf[j];
}

extern "C" void kernel_launch(void* const* d_in, const int* in_sizes, int n_in,
                              void* d_out, int out_size, void* d_ws, size_t ws_size,
                              hipStream_t stream) {
    const float* x = (const float*)d_in[0];
    const float* cb = (const float*)d_in[1];
    float* c2n = (float*)d_ws;                                      // 4 KB
    unsigned short* G = (unsigned short*)((char*)d_ws + 4096);      // 256 KB image

    hipLaunchKernelGGL(prep_kernel, dim3(KCB * 8 / 256), dim3(256), 0, stream, cb, G, c2n);
    hipLaunchKernelGGL(vq_main, dim3(NPTS / PPB), dim3(512), 0, stream,
                       x, cb, c2n, G, (float*)d_out);
}